// Round 6
// baseline (2473.393 us; speedup 1.0000x reference)
//
#include <hip/hip_runtime.h>
#include <hip/hip_bf16.h>

#define DD 128

typedef __attribute__((ext_vector_type(8))) short bf16x8;
typedef __attribute__((ext_vector_type(4))) float f32x4;

// split 8 fp32 -> packed bf16 hi (truncate) and lo (truncate of residual)
__device__ __forceinline__ void cvt8(const float4 a0, const float4 a1,
                                     bf16x8& hi, bf16x8& lo)
{
    float af[8] = {a0.x, a0.y, a0.z, a0.w, a1.x, a1.y, a1.z, a1.w};
    union { unsigned int u[4]; bf16x8 v; } H, L;
    #pragma unroll
    for (int i = 0; i < 4; ++i) {
        unsigned int b0 = __float_as_uint(af[2*i]);
        unsigned int b1 = __float_as_uint(af[2*i+1]);
        unsigned int h0 = b0 & 0xFFFF0000u;
        unsigned int h1 = b1 & 0xFFFF0000u;
        H.u[i] = (h0 >> 16) | h1;
        float r0 = af[2*i]   - __uint_as_float(h0);
        float r1 = af[2*i+1] - __uint_as_float(h1);
        L.u[i] = (__float_as_uint(r0) >> 16) | (__float_as_uint(r1) & 0xFFFF0000u);
    }
    hi = H.v; lo = L.v;
}

__device__ __forceinline__ unsigned short f2bf_rtne(float x)
{
    unsigned int u = __float_as_uint(x);
    u += 0x7FFFu + ((u >> 16) & 1u);
    return (unsigned short)(u >> 16);
}

// Y[n][scol] = act( X[n][:] @ Wunit[cb] + bias[cb*128+...] )
// qvRemap: kqvs layout [K | QV-interleaved(q0 q1 v0 v1 ...) | Sk]
__global__ __launch_bounds__(256) void gemm_mfma(
    const float* __restrict__ X, const unsigned short* __restrict__ Wt,
    const float* __restrict__ bias, float* __restrict__ Y,
    int N, int ldY, int act, int qvRemap)
{
    const int lane = threadIdx.x & 63;
    const int wid  = threadIdx.x >> 6;
    const int wr = wid >> 1, wc = wid & 1;
    const int row0 = blockIdx.x * 128 + wr * 64;
    const int cb   = blockIdx.y;
    const unsigned short* WtH = Wt + (size_t)cb * 32768;
    const unsigned short* WtL = WtH + 16384;

    const int l15 = lane & 15;
    const int kg  = (lane >> 4) * 8;

    f32x4 acc[4][4] = {};

    int arow[4];
    #pragma unroll
    for (int mi = 0; mi < 4; ++mi) {
        int r = row0 + mi * 16 + l15;
        arow[mi] = r < N ? r : N - 1;
    }

    #pragma unroll
    for (int kc = 0; kc < 4; ++kc) {
        const int kb = kc * 32 + kg;
        bf16x8 ah[4], al[4], bh[4], bl[4];
        #pragma unroll
        for (int mi = 0; mi < 4; ++mi) {
            const float* p = X + (size_t)arow[mi] * DD + kb;
            float4 a0 = *(const float4*)p;
            float4 a1 = *(const float4*)(p + 4);
            cvt8(a0, a1, ah[mi], al[mi]);
        }
        #pragma unroll
        for (int ni = 0; ni < 4; ++ni) {
            int m = wc * 64 + ni * 16 + l15;
            bh[ni] = *(const bf16x8*)(WtH + (size_t)m * DD + kb);
            bl[ni] = *(const bf16x8*)(WtL + (size_t)m * DD + kb);
        }
        #pragma unroll
        for (int mi = 0; mi < 4; ++mi)
            #pragma unroll
            for (int ni = 0; ni < 4; ++ni) {
                acc[mi][ni] = __builtin_amdgcn_mfma_f32_16x16x32_bf16(ah[mi], bh[ni], acc[mi][ni], 0, 0, 0);
                acc[mi][ni] = __builtin_amdgcn_mfma_f32_16x16x32_bf16(ah[mi], bl[ni], acc[mi][ni], 0, 0, 0);
                acc[mi][ni] = __builtin_amdgcn_mfma_f32_16x16x32_bf16(al[mi], bh[ni], acc[mi][ni], 0, 0, 0);
            }
    }

    #pragma unroll
    for (int ni = 0; ni < 4; ++ni) {
        int colL = cb * 128 + wc * 64 + ni * 16 + l15;   // logical col (bias)
        float bv = bias[colL];
        int scol;
        if (qvRemap) {
            int cbb = colL >> 7, m = colL & 127;
            scol = (cbb == 0) ? m
                 : (cbb == 3) ? 384 + m
                 : 128 + ((m >> 1) << 2) + ((cbb - 1) << 1) + (m & 1);
        } else scol = colL;
        #pragma unroll
        for (int mi = 0; mi < 4; ++mi) {
            #pragma unroll
            for (int r = 0; r < 4; ++r) {
                int row = row0 + mi * 16 + (lane >> 4) * 4 + r;
                if (row < N) {
                    float v = acc[mi][ni][r] + bv;
                    Y[(size_t)row * ldY + scol] = act ? fmaxf(v, 0.f) : v;
                }
            }
        }
    }
}

// et[e][128] = bf16( ea[perm[clo+e]][0..20] @ We + be ) for e in [0,len), chunk-local.
// ea rows gathered via perm through LDS; K padded to 32.
__global__ __launch_bounds__(256) void gemm_et(
    const float* __restrict__ ea, const int* __restrict__ perm,
    const unsigned short* __restrict__ WeU, const float* __restrict__ be,
    unsigned short* __restrict__ et, int clo, int len)
{
    __shared__ float lds[128 * 33];
    const int tid = threadIdx.x;
    const int e0  = blockIdx.x * 128;

    #pragma unroll
    for (int it = 0; it < 16; ++it) {
        int idx = tid + it * 256;          // 0..4095
        int r = idx >> 5, cc = idx & 31;
        float v = 0.f;
        if (cc < 21 && (e0 + r) < len)
            v = ea[(size_t)perm[clo + e0 + r] * 21 + cc];
        lds[r * 33 + cc] = v;
    }
    __syncthreads();

    const int lane = tid & 63;
    const int wid  = tid >> 6;
    const int wr = wid >> 1, wc = wid & 1;
    const int l15 = lane & 15;
    const int kg  = (lane >> 4) * 8;

    const unsigned short* WH = WeU;
    const unsigned short* WL = WeU + 4096;

    f32x4 acc[4][4] = {};
    bf16x8 ah[4], al[4], bh[4], bl[4];

    #pragma unroll
    for (int mi = 0; mi < 4; ++mi) {
        int lr = wr * 64 + mi * 16 + l15;
        const float* p = lds + lr * 33 + kg;
        float4 a0 = make_float4(p[0], p[1], p[2], p[3]);
        float4 a1 = make_float4(p[4], p[5], p[6], p[7]);
        cvt8(a0, a1, ah[mi], al[mi]);
    }
    #pragma unroll
    for (int ni = 0; ni < 4; ++ni) {
        int m = wc * 64 + ni * 16 + l15;
        bh[ni] = *(const bf16x8*)(WH + (size_t)m * 32 + kg);
        bl[ni] = *(const bf16x8*)(WL + (size_t)m * 32 + kg);
    }
    #pragma unroll
    for (int mi = 0; mi < 4; ++mi)
        #pragma unroll
        for (int ni = 0; ni < 4; ++ni) {
            acc[mi][ni] = __builtin_amdgcn_mfma_f32_16x16x32_bf16(ah[mi], bh[ni], acc[mi][ni], 0, 0, 0);
            acc[mi][ni] = __builtin_amdgcn_mfma_f32_16x16x32_bf16(ah[mi], bl[ni], acc[mi][ni], 0, 0, 0);
            acc[mi][ni] = __builtin_amdgcn_mfma_f32_16x16x32_bf16(al[mi], bh[ni], acc[mi][ni], 0, 0, 0);
        }

    #pragma unroll
    for (int ni = 0; ni < 4; ++ni) {
        int col = wc * 64 + ni * 16 + l15;
        float bv = be[col];
        #pragma unroll
        for (int mi = 0; mi < 4; ++mi) {
            #pragma unroll
            for (int r = 0; r < 4; ++r) {
                int lr = wr * 64 + mi * 16 + (lane >> 4) * 4 + r;
                if (e0 + lr < len)
                    et[(size_t)(e0 + lr) * DD + col] = f2bf_rtne(acc[mi][ni][r] + bv);
            }
        }
    }
}

// one-time: transpose+split weight units to bf16 hi/lo [m][k].
__global__ __launch_bounds__(256) void prep_weights(
    const float* __restrict__ embW, const float* __restrict__ keyW,
    const float* __restrict__ qryW, const float* __restrict__ valW,
    const float* __restrict__ skpW, const float* __restrict__ g1W,
    const float* __restrict__ g2W, const float* __restrict__ h1W,
    const float* __restrict__ h2W, const float* __restrict__ edgW,
    const float* __restrict__ keyb, const float* __restrict__ qryb,
    const float* __restrict__ valb, const float* __restrict__ skpb,
    unsigned short* __restrict__ Wt, float* __restrict__ biasCat)
{
    const int u = blockIdx.x;   // 0..16
    const int t = threadIdx.x;
    __shared__ float T[128][129];

    if (u < 15) {
        const float* src;
        if (u < 3)       src = embW + (size_t)u * 16384;
        else if (u < 7)  { const float* p[4] = {keyW, qryW, valW, skpW}; src = p[u - 3]; }
        else if (u < 11) { const float* p[4] = {keyW, qryW, valW, skpW}; src = p[u - 7] + 16384; }
        else if (u == 11) src = g1W;
        else if (u == 12) src = g2W;
        else if (u == 13) src = h1W;
        else              src = h2W;

        #pragma unroll
        for (int i = 0; i < 64; ++i) {
            int idx = t + 256 * i;
            T[idx >> 7][idx & 127] = src[idx];
        }
        __syncthreads();

        unsigned short* dH = Wt + (size_t)u * 32768;
        unsigned short* dL = dH + 16384;
        const int m = t >> 1, kbase = (t & 1) * 64;
        for (int j = 0; j < 64; ++j) {
            int k = kbase + j;
            float a = T[k][m];
            unsigned int b = __float_as_uint(a);
            unsigned int h = b & 0xFFFF0000u;
            float r = a - __uint_as_float(h);
            dH[m * 128 + k] = (unsigned short)(h >> 16);
            dL[m * 128 + k] = (unsigned short)(__float_as_uint(r) >> 16);
        }

        if (u == 0) {
            for (int x = t; x < 1024; x += 256) {
                int L = x >> 9, c = x & 511;
                const float* bp = (c < 128) ? keyb : (c < 256) ? qryb : (c < 384) ? valb : skpb;
                biasCat[x] = bp[L * 128 + (c & 127)];
            }
        }
    } else {
        const int layer = u - 15;
        const float* src = edgW + (size_t)layer * 21 * 128;   // [21][128]
        for (int x = t; x < 21 * 128; x += 256)
            T[x >> 7][x & 127] = src[x];
        __syncthreads();

        unsigned short* dH = Wt + (size_t)15 * 32768 + (size_t)layer * 8192;
        unsigned short* dL = dH + 4096;
        const int m = t >> 1, k0 = (t & 1) * 16;
        for (int j = 0; j < 16; ++j) {
            int k = k0 + j;
            float a = (k < 21) ? T[k][m] : 0.f;
            unsigned int b = __float_as_uint(a);
            unsigned int h = b & 0xFFFF0000u;
            float r = a - __uint_as_float(h);
            dH[m * 32 + k] = (unsigned short)(h >> 16);
            dL[m * 32 + k] = (unsigned short)(__float_as_uint(r) >> 16);
        }
    }
}

// ---------------- CSR build ----------------
__global__ void hist_kernel(const int* __restrict__ dstA, int* __restrict__ hist, int E)
{
    for (int e = blockIdx.x * blockDim.x + threadIdx.x; e < E;
         e += gridDim.x * blockDim.x)
        atomicAdd(&hist[dstA[e]], 1);
}

__global__ __launch_bounds__(256) void scan1_kernel(
    const int* __restrict__ in, int n_in,
    int* __restrict__ out, int* __restrict__ bsum, int n)
{
    __shared__ int wtot[4];
    const int t = threadIdx.x, lane = t & 63, wv = t >> 6;
    const int base = blockIdx.x * 1024 + t * 4;
    int v[4]; int sum = 0;
    #pragma unroll
    for (int j = 0; j < 4; ++j) {
        int idx = base + j;
        v[j] = (idx < n_in) ? in[idx] : 0;
        sum += v[j];
    }
    int incl = sum;
    #pragma unroll
    for (int d = 1; d < 64; d <<= 1) {
        int y = __shfl_up(incl, d, 64);
        if (lane >= d) incl += y;
    }
    if (lane == 63) wtot[wv] = incl;
    __syncthreads();
    int woff = 0;
    for (int w = 0; w < wv; ++w) woff += wtot[w];
    int run = woff + incl - sum;
    #pragma unroll
    for (int j = 0; j < 4; ++j) {
        int idx = base + j;
        if (idx < n) out[idx] = run;
        run += v[j];
    }
    if (t == 0)
        bsum[blockIdx.x] = wtot[0] + wtot[1] + wtot[2] + wtot[3];
}

__global__ void scan2_kernel(int* __restrict__ bsum, int nb)
{
    if (blockIdx.x == 0 && threadIdx.x == 0) {
        int run = 0;
        for (int i = 0; i < nb; ++i) { int t = bsum[i]; bsum[i] = run; run += t; }
    }
}

__global__ __launch_bounds__(256) void scan3_kernel(
    int* __restrict__ out, const int* __restrict__ bsum,
    int* __restrict__ cursor, int n, int n_nodes)
{
    const int base = blockIdx.x * 1024 + threadIdx.x * 4;
    const int add = bsum[blockIdx.x];
    #pragma unroll
    for (int j = 0; j < 4; ++j) {
        int idx = base + j;
        if (idx < n) {
            int vv = out[idx] + add;
            out[idx] = vv;
            if (idx < n_nodes) cursor[idx] = vv;
        }
    }
}

__global__ void scatter_kernel(const int* __restrict__ srcA, const int* __restrict__ dstA,
                               int* __restrict__ cursor, int* __restrict__ perm,
                               int* __restrict__ srcp, int E)
{
    for (int e = blockIdx.x * blockDim.x + threadIdx.x; e < E;
         e += gridDim.x * blockDim.x) {
        int d = dstA[e];
        int pos = atomicAdd(&cursor[d], 1);
        perm[pos] = e;
        srcp[pos] = srcA[e];
    }
}

// ---------------- edge aggregation: wave per dst, et precomputed, chunked ----------
// fused layout: [K | QV-interleaved | Sk]; accumulates into Sk block of fused.
__global__ __launch_bounds__(256) void edge_agg5(
    const int* __restrict__ row_ptr, const int* __restrict__ srcp,
    const unsigned short* __restrict__ et, int clo, int chi,
    float* __restrict__ fused, int N)
{
    const int wv = threadIdx.x >> 6, lane = threadIdx.x & 63;
    const int d = blockIdx.x * 4 + wv;
    if (d >= N) return;

    const int i0 = row_ptr[d], i1 = row_ptr[d + 1];
    int lo = i0 > clo ? i0 : clo;
    int hi = i1 < chi ? i1 : chi;
    if (lo >= hi) return;

    const int c = lane * 2;
    const float2 kd = *(const float2*)(fused + (size_t)d * 512 + c);

    float ax = 0.f, ay = 0.f;
    for (int i = lo; i < hi; i += 4) {
        int idx4[4]; unsigned int eu[4];
        float4 qv[4];
        #pragma unroll
        for (int t = 0; t < 4; ++t) {
            int ii = i + t; if (ii >= hi) ii = hi - 1;
            idx4[t] = srcp[ii];
            eu[t] = *(const unsigned int*)(et + (size_t)(ii - clo) * DD + c);
        }
        #pragma unroll
        for (int t = 0; t < 4; ++t)
            qv[t] = *(const float4*)(fused + (size_t)idx4[t] * 512 + 128 + lane * 4);
        #pragma unroll
        for (int t = 0; t < 4; ++t) {
            if (i + t >= hi) break;   // wave-uniform
            float ex = __uint_as_float((eu[t] & 0xFFFFu) << 16);
            float ey = __uint_as_float(eu[t] & 0xFFFF0000u);
            float zx = kd.x + qv[t].x + ex;
            float zy = kd.y + qv[t].y + ey;
            float gx = 1.f / (1.f + __expf(-zx));
            float gy = 1.f / (1.f + __expf(-zy));
            ax = fmaf(gx, qv[t].z, ax);
            ay = fmaf(gy, qv[t].w, ay);
        }
    }
    float* accp = fused + (size_t)d * 512 + 384 + c;
    float2 old = *(float2*)accp;
    old.x += ax; old.y += ay;
    *(float2*)accp = old;
}

// fallback (no ws slack): wave per dst, inline edge MLP, raw ea via perm; writes X=relu(...)
__global__ __launch_bounds__(256) void edge_aggF(
    const int* __restrict__ row_ptr, const int* __restrict__ srcp,
    const float* __restrict__ ea, const int* __restrict__ perm,
    const float* __restrict__ We, const float* __restrict__ be,
    const float* __restrict__ fused, float* __restrict__ X, int N)
{
    const int wv = threadIdx.x >> 6, lane = threadIdx.x & 63;
    const int d = blockIdx.x * 4 + wv;
    if (d >= N) return;
    const int c = lane * 2;

    float2 w[21];
    #pragma unroll
    for (int j = 0; j < 21; ++j)
        w[j] = *(const float2*)(We + j * DD + c);
    const float2 b2 = *(const float2*)(be + c);
    const float2 kd = *(const float2*)(fused + (size_t)d * 512 + c);
    const float2 sk = *(const float2*)(fused + (size_t)d * 512 + 384 + c);

    float ax = 0.f, ay = 0.f;
    const int i0 = row_ptr[d], i1 = row_ptr[d + 1];
    for (int i = i0; i < i1; ++i) {
        const float* eap = ea + (size_t)perm[i] * 21;
        const int s = srcp[i];
        float4 qv = *(const float4*)(fused + (size_t)s * 512 + 128 + lane * 4);
        float ex = b2.x, ey = b2.y;
        #pragma unroll
        for (int j = 0; j < 21; ++j) {
            float a = eap[j];
            ex = fmaf(a, w[j].x, ex);
            ey = fmaf(a, w[j].y, ey);
        }
        float zx = kd.x + qv.x + ex;
        float zy = kd.y + qv.y + ey;
        ax = fmaf(1.f / (1.f + __expf(-zx)), qv.z, ax);
        ay = fmaf(1.f / (1.f + __expf(-zy)), qv.w, ay);
    }
    X[(size_t)d * DD + c]     = fmaxf(ax + sk.x, 0.f);
    X[(size_t)d * DD + c + 1] = fmaxf(ay + sk.y, 0.f);
}

// X = relu(Sk block of fused)
__global__ void relu_sk(const float* __restrict__ fused, float* __restrict__ X, long n4)
{
    for (long idx = (long)blockIdx.x * blockDim.x + threadIdx.x; idx < n4;
         idx += (long)gridDim.x * blockDim.x) {
        long n = idx >> 5; int j = (int)(idx & 31);
        float4 v = *(const float4*)(fused + (size_t)n * 512 + 384 + j * 4);
        v.x = fmaxf(v.x, 0.f); v.y = fmaxf(v.y, 0.f);
        v.z = fmaxf(v.z, 0.f); v.w = fmaxf(v.w, 0.f);
        *(float4*)(X + (size_t)n * DD + j * 4) = v;
    }
}

// column sums of x[N][128] into gsum[128] (gsum pre-zeroed)
__global__ void colsum_kernel(const float* __restrict__ x, float* __restrict__ gsum, int N)
{
    const int c = threadIdx.x;
    float acc = 0.f;
    for (int r = blockIdx.x; r < N; r += gridDim.x)
        acc += x[(size_t)r * DD + c];
    atomicAdd(&gsum[c], acc);
}

__global__ void cvec_kernel(const float* __restrict__ gsum, const float* __restrict__ h1W,
                            const float* __restrict__ h1b, float* __restrict__ cvec, float invN)
{
    const int m = threadIdx.x;
    float acc = h1b[m];
    for (int k = 0; k < 128; ++k)
        acc = fmaf(gsum[k] * invN, h1W[(size_t)(128 + k) * DD + m], acc);
    cvec[m] = acc;
}

__global__ __launch_bounds__(256) void head3_kernel(
    const float* __restrict__ x, const float* __restrict__ w,
    const float* __restrict__ b, float* __restrict__ out, int N)
{
    const int wave = threadIdx.x >> 6;
    const int lane = threadIdx.x & 63;
    const long n = (long)blockIdx.x * 4 + wave;
    if (n >= N) return;
    float acc = x[n * DD + lane] * w[lane] + x[n * DD + 64 + lane] * w[64 + lane];
    #pragma unroll
    for (int off = 32; off > 0; off >>= 1)
        acc += __shfl_down(acc, off, 64);
    if (lane == 0) out[n] = acc + b[0];
}

extern "C" void kernel_launch(void* const* d_in, const int* in_sizes, int n_in,
                              void* d_out, int out_size, void* d_ws, size_t ws_size,
                              hipStream_t stream)
{
    const float* G    = (const float*)d_in[0];
    const int*   ei   = (const int*)  d_in[1];
    const float* ea   = (const float*)d_in[2];
    const float* embW = (const float*)d_in[3];
    const float* embb = (const float*)d_in[4];
    const float* keyW = (const float*)d_in[5];
    const float* keyb = (const float*)d_in[6];
    const float* qryW = (const float*)d_in[7];
    const float* qryb = (const float*)d_in[8];
    const float* valW = (const float*)d_in[9];
    const float* valb = (const float*)d_in[10];
    const float* skpW = (const float*)d_in[11];
    const float* skpb = (const float*)d_in[12];
    const float* edgW = (const float*)d_in[13];
    const float* edgb = (const float*)d_in[14];
    const float* g1W  = (const float*)d_in[15];
    const float* g1b  = (const float*)d_in[16];
    const float* g2W  = (const float*)d_in[17];
    const float* g2b  = (const float*)d_in[18];
    const float* h1W  = (const float*)d_in[19];
    const float* h1b  = (const float*)d_in[20];
    const float* h2W  = (const float*)d_in[21];
    const float* h2b  = (const float*)d_in[22];
    const float* h3W  = (const float*)d_in[23];
    const float* h3b  = (const float*)d_in[24];

    const int N = in_sizes[0] / DD;    // 100000
    const int E = in_sizes[2] / 21;    // 1000000
    const int* srcA = ei;
    const int* dstA = ei + E;

    const size_t S = (size_t)N * DD;
    float* bx     = (float*)d_ws;      // [N][128]
    float* b2     = bx + S;            // [N][128]
    float* bfused = b2 + S;            // [N][512]  (K | QV | Sk-accumulator)
    float* gsum   = bfused + (size_t)N * 512;   // 128
    float* cvec   = gsum + DD;         // 128
    float* biasCat= cvec + DD;         // 1024
    unsigned short* Wt = (unsigned short*)(biasCat + 1024);  // 15*32768 + 2*8192 ushorts
    int* hist = (int*)((char*)Wt + ((size_t)15 * 32768 + 2 * 8192) * 2);  // N
    int* row  = hist + N;              // N+1
    int* cur  = row + N + 1;           // N
    int* bsum = cur + N;               // 128
    int* perm = bsum + 128;            // E
    int* srcp = perm + E;              // E
    unsigned short* et = (unsigned short*)(srcp + E);   // chunk buffer (remainder)

    const size_t base_bytes = (size_t)((char*)et - (char*)d_ws);
    const size_t slack = ws_size > base_bytes ? ws_size - base_bytes : 0;
    long cap = (long)(slack / ((size_t)DD * 2));
    cap &= ~127L;
    const bool useEt = cap >= 32768;
    if (cap > (long)E) cap = ((long)E + 127L) & ~127L;
    const int nch = useEt ? (int)(((long)E + cap - 1) / cap) : 0;

    const dim3 g1grid((N + 127) / 128, 1);
    const dim3 g4grid((N + 127) / 128, 4);
    const int aggGrid = (N + 3) / 4;
    const int waveGrid = (N + 3) / 4;
    const int nScan = N + 1;
    const int nb = (nScan + 1023) / 1024;

    // ---- weight prep + CSR build ----
    prep_weights<<<17, 256, 0, stream>>>(embW, keyW, qryW, valW, skpW,
                                         g1W, g2W, h1W, h2W, edgW,
                                         keyb, qryb, valb, skpb, Wt, biasCat);
    hipMemsetAsync(hist, 0, (size_t)N * sizeof(int), stream);
    hist_kernel<<<1024, 256, 0, stream>>>(dstA, hist, E);
    scan1_kernel<<<nb, 256, 0, stream>>>(hist, N, row, bsum, nScan);
    scan2_kernel<<<1, 64, 0, stream>>>(bsum, nb);
    scan3_kernel<<<nb, 256, 0, stream>>>(row, bsum, cur, nScan, N);
    scatter_kernel<<<1024, 256, 0, stream>>>(srcA, dstA, cur, perm, srcp, E);

    #define UNIT(u) (Wt + (size_t)(u) * 32768)
    #define EUNIT(l) (Wt + (size_t)15 * 32768 + (size_t)(l) * 8192)

    // ---- embedding MLP: G -> bx -> b2 -> bx ----
    gemm_mfma<<<g1grid, 256, 0, stream>>>(G,  UNIT(0), embb + 0,    bx, N, DD, 1, 0);
    gemm_mfma<<<g1grid, 256, 0, stream>>>(bx, UNIT(1), embb + DD,   b2, N, DD, 1, 0);
    gemm_mfma<<<g1grid, 256, 0, stream>>>(b2, UNIT(2), embb + 2*DD, bx, N, DD, 1, 0);

    // ---- conv layers ----
    const float* xin  = bx;
    float*       xout = b2;
    for (int L = 0; L < 2; ++L) {
        gemm_mfma<<<g4grid, 256, 0, stream>>>(xin, UNIT(3 + 4*L), biasCat + 512*L,
                                              bfused, N, 512, 0, 1);
        if (useEt) {
            for (int ci = 0; ci < nch; ++ci) {
                int clo = (int)((long)ci * cap);
                int chi = (long)clo + cap < (long)E ? (int)(clo + cap) : E;
                int len = chi - clo;
                gemm_et<<<(len + 127) / 128, 256, 0, stream>>>(
                    ea, perm, EUNIT(L), edgb + DD*L, et, clo, len);
                edge_agg5<<<aggGrid, 256, 0, stream>>>(row, srcp, et, clo, chi, bfused, N);
            }
            relu_sk<<<2048, 256, 0, stream>>>(bfused, xout, (long)N * 32);
        } else {
            edge_aggF<<<aggGrid, 256, 0, stream>>>(row, srcp, ea, perm,
                                                   edgW + 21*DD*L, edgb + DD*L,
                                                   bfused, xout, N);
        }
        // swap
        const float* t = xin; xin = xout; xout = (float*)t;
    }
    // after 2 layers: x lives in bx (b2 -> bx swap sequence: L0 out b2, L1 out bx)

    // ---- graph linears: bx -> b2 (relu) -> bx ----
    gemm_mfma<<<g1grid, 256, 0, stream>>>(bx, UNIT(11), g1b, b2, N, DD, 1, 0);
    gemm_mfma<<<g1grid, 256, 0, stream>>>(b2, UNIT(12), g2b, bx, N, DD, 0, 0);

    // ---- graph mean -> cvec ----
    hipMemsetAsync(gsum, 0, DD * sizeof(float), stream);
    colsum_kernel<<<256, DD, 0, stream>>>(bx, gsum, N);
    cvec_kernel<<<1, DD, 0, stream>>>(gsum, h1W, h1b, cvec, 1.0f / (float)N);

    // ---- head: h1 (bias=cvec, relu) -> b2 ; h2 -> bx ; h3 -> out ----
    gemm_mfma<<<g1grid, 256, 0, stream>>>(bx, UNIT(13), cvec, b2, N, DD, 1, 0);
    gemm_mfma<<<g1grid, 256, 0, stream>>>(b2, UNIT(14), h2b, bx, N, DD, 1, 0);
    head3_kernel<<<waveGrid, 256, 0, stream>>>(bx, h3W, h3b, (float*)d_out, N);
}

// Round 7
// 1748.036 us; speedup vs baseline: 1.4150x; 1.4150x over previous
//
#include <hip/hip_runtime.h>
#include <hip/hip_bf16.h>

#define DD 128

typedef __attribute__((ext_vector_type(8))) short bf16x8;
typedef __attribute__((ext_vector_type(4))) float f32x4;

// split 8 fp32 -> packed bf16 hi (truncate) and lo (truncate of residual)
__device__ __forceinline__ void cvt8(const float4 a0, const float4 a1,
                                     bf16x8& hi, bf16x8& lo)
{
    float af[8] = {a0.x, a0.y, a0.z, a0.w, a1.x, a1.y, a1.z, a1.w};
    union { unsigned int u[4]; bf16x8 v; } H, L;
    #pragma unroll
    for (int i = 0; i < 4; ++i) {
        unsigned int b0 = __float_as_uint(af[2*i]);
        unsigned int b1 = __float_as_uint(af[2*i+1]);
        unsigned int h0 = b0 & 0xFFFF0000u;
        unsigned int h1 = b1 & 0xFFFF0000u;
        H.u[i] = (h0 >> 16) | h1;
        float r0 = af[2*i]   - __uint_as_float(h0);
        float r1 = af[2*i+1] - __uint_as_float(h1);
        L.u[i] = (__float_as_uint(r0) >> 16) | (__float_as_uint(r1) & 0xFFFF0000u);
    }
    hi = H.v; lo = L.v;
}

// Y[n][cb*128+...] = act( X[n][:] @ Wunit[cb] + bias[cb*128+...] ), linear stores
__global__ __launch_bounds__(256) void gemm_mfma(
    const float* __restrict__ X, const unsigned short* __restrict__ Wt,
    const float* __restrict__ bias, float* __restrict__ Y,
    int N, int ldY, int act)
{
    const int lane = threadIdx.x & 63;
    const int wid  = threadIdx.x >> 6;
    const int wr = wid >> 1, wc = wid & 1;
    const int row0 = blockIdx.x * 128 + wr * 64;
    const int cb   = blockIdx.y;
    const unsigned short* WtH = Wt + (size_t)cb * 32768;
    const unsigned short* WtL = WtH + 16384;

    const int l15 = lane & 15;
    const int kg  = (lane >> 4) * 8;

    f32x4 acc[4][4] = {};

    int arow[4];
    #pragma unroll
    for (int mi = 0; mi < 4; ++mi) {
        int r = row0 + mi * 16 + l15;
        arow[mi] = r < N ? r : N - 1;
    }

    #pragma unroll
    for (int kc = 0; kc < 4; ++kc) {
        const int kb = kc * 32 + kg;
        bf16x8 ah[4], al[4], bh[4], bl[4];
        #pragma unroll
        for (int mi = 0; mi < 4; ++mi) {
            const float* p = X + (size_t)arow[mi] * DD + kb;
            float4 a0 = *(const float4*)p;
            float4 a1 = *(const float4*)(p + 4);
            cvt8(a0, a1, ah[mi], al[mi]);
        }
        #pragma unroll
        for (int ni = 0; ni < 4; ++ni) {
            int m = wc * 64 + ni * 16 + l15;
            bh[ni] = *(const bf16x8*)(WtH + (size_t)m * DD + kb);
            bl[ni] = *(const bf16x8*)(WtL + (size_t)m * DD + kb);
        }
        #pragma unroll
        for (int mi = 0; mi < 4; ++mi)
            #pragma unroll
            for (int ni = 0; ni < 4; ++ni) {
                acc[mi][ni] = __builtin_amdgcn_mfma_f32_16x16x32_bf16(ah[mi], bh[ni], acc[mi][ni], 0, 0, 0);
                acc[mi][ni] = __builtin_amdgcn_mfma_f32_16x16x32_bf16(ah[mi], bl[ni], acc[mi][ni], 0, 0, 0);
                acc[mi][ni] = __builtin_amdgcn_mfma_f32_16x16x32_bf16(al[mi], bh[ni], acc[mi][ni], 0, 0, 0);
            }
    }

    const int colW = cb * 128 + wc * 64;
    #pragma unroll
    for (int ni = 0; ni < 4; ++ni) {
        float bv = bias[colW + ni * 16 + l15];
        #pragma unroll
        for (int mi = 0; mi < 4; ++mi) {
            #pragma unroll
            for (int r = 0; r < 4; ++r) {
                int row = row0 + mi * 16 + (lane >> 4) * 4 + r;
                if (row < N) {
                    float v = acc[mi][ni][r] + bv;
                    Y[(size_t)row * ldY + colW + ni * 16 + l15] = act ? fmaxf(v, 0.f) : v;
                }
            }
        }
    }
}

// one-time: transpose+split weight units to bf16 hi/lo [m][k].
__global__ __launch_bounds__(256) void prep_weights(
    const float* __restrict__ embW, const float* __restrict__ keyW,
    const float* __restrict__ qryW, const float* __restrict__ valW,
    const float* __restrict__ skpW, const float* __restrict__ g1W,
    const float* __restrict__ g2W, const float* __restrict__ h1W,
    const float* __restrict__ h2W,
    const float* __restrict__ keyb, const float* __restrict__ qryb,
    const float* __restrict__ valb, const float* __restrict__ skpb,
    unsigned short* __restrict__ Wt, float* __restrict__ biasCat)
{
    const int u = blockIdx.x;   // 0..14
    const int t = threadIdx.x;
    __shared__ float T[128][129];

    const float* src;
    if (u < 3)       src = embW + (size_t)u * 16384;
    else if (u < 7)  { const float* p[4] = {keyW, qryW, valW, skpW}; src = p[u - 3]; }
    else if (u < 11) { const float* p[4] = {keyW, qryW, valW, skpW}; src = p[u - 7] + 16384; }
    else if (u == 11) src = g1W;
    else if (u == 12) src = g2W;
    else if (u == 13) src = h1W;
    else              src = h2W;

    #pragma unroll
    for (int i = 0; i < 64; ++i) {
        int idx = t + 256 * i;
        T[idx >> 7][idx & 127] = src[idx];
    }
    __syncthreads();

    unsigned short* dH = Wt + (size_t)u * 32768;
    unsigned short* dL = dH + 16384;
    const int m = t >> 1, kbase = (t & 1) * 64;
    for (int j = 0; j < 64; ++j) {
        int k = kbase + j;
        float a = T[k][m];
        unsigned int b = __float_as_uint(a);
        unsigned int h = b & 0xFFFF0000u;
        float r = a - __uint_as_float(h);
        dH[m * 128 + k] = (unsigned short)(h >> 16);
        dL[m * 128 + k] = (unsigned short)(__float_as_uint(r) >> 16);
    }

    if (u == 0) {
        for (int x = t; x < 1024; x += 256) {
            int L = x >> 9, c = x & 511;
            const float* bp = (c < 128) ? keyb : (c < 256) ? qryb : (c < 384) ? valb : skpb;
            biasCat[x] = bp[L * 128 + (c & 127)];
        }
    }
}

// ---------------- CSR build ----------------
__global__ void hist_kernel(const int* __restrict__ dstA, int* __restrict__ hist, int E)
{
    for (int e = blockIdx.x * blockDim.x + threadIdx.x; e < E;
         e += gridDim.x * blockDim.x)
        atomicAdd(&hist[dstA[e]], 1);
}

__global__ __launch_bounds__(256) void scan1_kernel(
    const int* __restrict__ in, int n_in,
    int* __restrict__ out, int* __restrict__ bsum, int n)
{
    __shared__ int wtot[4];
    const int t = threadIdx.x, lane = t & 63, wv = t >> 6;
    const int base = blockIdx.x * 1024 + t * 4;
    int v[4]; int sum = 0;
    #pragma unroll
    for (int j = 0; j < 4; ++j) {
        int idx = base + j;
        v[j] = (idx < n_in) ? in[idx] : 0;
        sum += v[j];
    }
    int incl = sum;
    #pragma unroll
    for (int d = 1; d < 64; d <<= 1) {
        int y = __shfl_up(incl, d, 64);
        if (lane >= d) incl += y;
    }
    if (lane == 63) wtot[wv] = incl;
    __syncthreads();
    int woff = 0;
    for (int w = 0; w < wv; ++w) woff += wtot[w];
    int run = woff + incl - sum;
    #pragma unroll
    for (int j = 0; j < 4; ++j) {
        int idx = base + j;
        if (idx < n) out[idx] = run;
        run += v[j];
    }
    if (t == 0)
        bsum[blockIdx.x] = wtot[0] + wtot[1] + wtot[2] + wtot[3];
}

__global__ void scan2_kernel(int* __restrict__ bsum, int nb)
{
    if (blockIdx.x == 0 && threadIdx.x == 0) {
        int run = 0;
        for (int i = 0; i < nb; ++i) { int t = bsum[i]; bsum[i] = run; run += t; }
    }
}

__global__ __launch_bounds__(256) void scan3_kernel(
    int* __restrict__ out, const int* __restrict__ bsum,
    int* __restrict__ cursor, int n, int n_nodes)
{
    const int base = blockIdx.x * 1024 + threadIdx.x * 4;
    const int add = bsum[blockIdx.x];
    #pragma unroll
    for (int j = 0; j < 4; ++j) {
        int idx = base + j;
        if (idx < n) {
            int vv = out[idx] + add;
            out[idx] = vv;
            if (idx < n_nodes) cursor[idx] = vv;
        }
    }
}

__global__ void scatter_kernel(const int* __restrict__ srcA, const int* __restrict__ dstA,
                               int* __restrict__ cursor, int* __restrict__ perm,
                               int* __restrict__ srcp, int E)
{
    for (int e = blockIdx.x * blockDim.x + threadIdx.x; e < E;
         e += gridDim.x * blockDim.x) {
        int d = dstA[e];
        int pos = atomicAdd(&cursor[d], 1);
        perm[pos] = e;
        srcp[pos] = srcA[e];
    }
}

// ---------------- edge aggregation: wave per dst, ILP-optimized ----------------
// fused layout per row: [K | Q | V | Sk] (4 x 128)
// per edge: vectorized ea row load (5xfloat4+1), 4-way split MLP chains,
// 2-edge unroll, branchless tail.
__global__ __launch_bounds__(256) void edge_agg6(
    const int* __restrict__ row_ptr, const int* __restrict__ srcp,
    const float* __restrict__ ea, const int* __restrict__ perm,
    const float* __restrict__ We, const float* __restrict__ be,
    const float* __restrict__ fused, float* __restrict__ X, int N)
{
    const int wv = threadIdx.x >> 6, lane = threadIdx.x & 63;
    const int d = blockIdx.x * 4 + wv;
    if (d >= N) return;
    const int c = lane * 2;

    float2 w[21];
    #pragma unroll
    for (int j = 0; j < 21; ++j)
        w[j] = *(const float2*)(We + j * DD + c);
    const float2 b2 = *(const float2*)(be + c);
    const float2 kd = *(const float2*)(fused + (size_t)d * 512 + c);
    const float2 sk = *(const float2*)(fused + (size_t)d * 512 + 384 + c);

    float ax = 0.f, ay = 0.f;
    const int i0 = row_ptr[d], i1 = row_ptr[d + 1];

    for (int i = i0; i < i1; i += 2) {
        const int iA = i;
        const int iB = (i + 1 < i1) ? i + 1 : i1 - 1;
        const float wgtB = (i + 1 < i1) ? 1.f : 0.f;

        const int sA = srcp[iA], sB = srcp[iB];
        const int pA = perm[iA], pB = perm[iB];

        // ---- ea rows (wave-uniform), vectorized ----
        const float* eA = ea + (size_t)pA * 21;
        const float* eB = ea + (size_t)pB * 21;
        float4 A0 = *(const float4*)(eA);      float4 B0 = *(const float4*)(eB);
        float4 A1 = *(const float4*)(eA + 4);  float4 B1 = *(const float4*)(eB + 4);
        float4 A2 = *(const float4*)(eA + 8);  float4 B2 = *(const float4*)(eB + 8);
        float4 A3 = *(const float4*)(eA + 12); float4 B3 = *(const float4*)(eB + 12);
        float4 A4 = *(const float4*)(eA + 16); float4 B4 = *(const float4*)(eB + 16);
        float A5 = eA[20], B5 = eB[20];

        // ---- gathers ----
        const float* fpA = fused + (size_t)sA * 512;
        const float* fpB = fused + (size_t)sB * 512;
        float2 qA = *(const float2*)(fpA + 128 + c);
        float2 vA = *(const float2*)(fpA + 256 + c);
        float2 qB = *(const float2*)(fpB + 128 + c);
        float2 vB = *(const float2*)(fpB + 256 + c);

        float aA[21] = {A0.x,A0.y,A0.z,A0.w, A1.x,A1.y,A1.z,A1.w,
                        A2.x,A2.y,A2.z,A2.w, A3.x,A3.y,A3.z,A3.w,
                        A4.x,A4.y,A4.z,A4.w, A5};
        float aB[21] = {B0.x,B0.y,B0.z,B0.w, B1.x,B1.y,B1.z,B1.w,
                        B2.x,B2.y,B2.z,B2.w, B3.x,B3.y,B3.z,B3.w,
                        B4.x,B4.y,B4.z,B4.w, B5};

        // ---- 4-way split dot products (independent chains) ----
        float pxA[4] = {0,0,0,0}, pyA[4] = {0,0,0,0};
        float pxB[4] = {0,0,0,0}, pyB[4] = {0,0,0,0};
        #pragma unroll
        for (int j = 0; j < 21; ++j) {
            int s = j & 3;
            pxA[s] = fmaf(aA[j], w[j].x, pxA[s]);
            pyA[s] = fmaf(aA[j], w[j].y, pyA[s]);
            pxB[s] = fmaf(aB[j], w[j].x, pxB[s]);
            pyB[s] = fmaf(aB[j], w[j].y, pyB[s]);
        }
        float exA = (pxA[0] + pxA[1]) + (pxA[2] + pxA[3]) + b2.x;
        float eyA = (pyA[0] + pyA[1]) + (pyA[2] + pyA[3]) + b2.y;
        float exB = (pxB[0] + pxB[1]) + (pxB[2] + pxB[3]) + b2.x;
        float eyB = (pyB[0] + pyB[1]) + (pyB[2] + pyB[3]) + b2.y;

        float zxA = kd.x + qA.x + exA;
        float zyA = kd.y + qA.y + eyA;
        float zxB = kd.x + qB.x + exB;
        float zyB = kd.y + qB.y + eyB;

        float gxA = 1.f / (1.f + __expf(-zxA));
        float gyA = 1.f / (1.f + __expf(-zyA));
        float gxB = wgtB / (1.f + __expf(-zxB));
        float gyB = wgtB / (1.f + __expf(-zyB));

        ax = fmaf(gxA, vA.x, ax);
        ay = fmaf(gyA, vA.y, ay);
        ax = fmaf(gxB, vB.x, ax);
        ay = fmaf(gyB, vB.y, ay);
    }

    X[(size_t)d * DD + c]     = fmaxf(ax + sk.x, 0.f);
    X[(size_t)d * DD + c + 1] = fmaxf(ay + sk.y, 0.f);
}

// column sums of x[N][128] into gsum[128] (gsum pre-zeroed)
__global__ void colsum_kernel(const float* __restrict__ x, float* __restrict__ gsum, int N)
{
    const int c = threadIdx.x;
    float acc = 0.f;
    for (int r = blockIdx.x; r < N; r += gridDim.x)
        acc += x[(size_t)r * DD + c];
    atomicAdd(&gsum[c], acc);
}

__global__ void cvec_kernel(const float* __restrict__ gsum, const float* __restrict__ h1W,
                            const float* __restrict__ h1b, float* __restrict__ cvec, float invN)
{
    const int m = threadIdx.x;
    float acc = h1b[m];
    for (int k = 0; k < 128; ++k)
        acc = fmaf(gsum[k] * invN, h1W[(size_t)(128 + k) * DD + m], acc);
    cvec[m] = acc;
}

__global__ __launch_bounds__(256) void head3_kernel(
    const float* __restrict__ x, const float* __restrict__ w,
    const float* __restrict__ b, float* __restrict__ out, int N)
{
    const int wave = threadIdx.x >> 6;
    const int lane = threadIdx.x & 63;
    const long n = (long)blockIdx.x * 4 + wave;
    if (n >= N) return;
    float acc = x[n * DD + lane] * w[lane] + x[n * DD + 64 + lane] * w[64 + lane];
    #pragma unroll
    for (int off = 32; off > 0; off >>= 1)
        acc += __shfl_down(acc, off, 64);
    if (lane == 0) out[n] = acc + b[0];
}

extern "C" void kernel_launch(void* const* d_in, const int* in_sizes, int n_in,
                              void* d_out, int out_size, void* d_ws, size_t ws_size,
                              hipStream_t stream)
{
    const float* G    = (const float*)d_in[0];
    const int*   ei   = (const int*)  d_in[1];
    const float* ea   = (const float*)d_in[2];
    const float* embW = (const float*)d_in[3];
    const float* embb = (const float*)d_in[4];
    const float* keyW = (const float*)d_in[5];
    const float* keyb = (const float*)d_in[6];
    const float* qryW = (const float*)d_in[7];
    const float* qryb = (const float*)d_in[8];
    const float* valW = (const float*)d_in[9];
    const float* valb = (const float*)d_in[10];
    const float* skpW = (const float*)d_in[11];
    const float* skpb = (const float*)d_in[12];
    const float* edgW = (const float*)d_in[13];
    const float* edgb = (const float*)d_in[14];
    const float* g1W  = (const float*)d_in[15];
    const float* g1b  = (const float*)d_in[16];
    const float* g2W  = (const float*)d_in[17];
    const float* g2b  = (const float*)d_in[18];
    const float* h1W  = (const float*)d_in[19];
    const float* h1b  = (const float*)d_in[20];
    const float* h2W  = (const float*)d_in[21];
    const float* h2b  = (const float*)d_in[22];
    const float* h3W  = (const float*)d_in[23];
    const float* h3b  = (const float*)d_in[24];

    const int N = in_sizes[0] / DD;    // 100000
    const int E = in_sizes[2] / 21;    // 1000000
    const int* srcA = ei;
    const int* dstA = ei + E;

    const size_t S = (size_t)N * DD;
    float* bx     = (float*)d_ws;      // [N][128]
    float* b2     = bx + S;            // [N][128]
    float* bfused = b2 + S;            // [N][512]  (K | Q | V | Sk)
    float* gsum   = bfused + (size_t)N * 512;   // 128
    float* cvec   = gsum + DD;         // 128
    float* biasCat= cvec + DD;         // 1024
    unsigned short* Wt = (unsigned short*)(biasCat + 1024);  // 15*32768 ushorts
    int* hist = (int*)((char*)Wt + (size_t)15 * 32768 * 2);  // N
    int* row  = hist + N;              // N+1
    int* cur  = row + N + 1;           // N
    int* bsum = cur + N;               // 128
    int* perm = bsum + 128;            // E
    int* srcp = perm + E;              // E

    const dim3 g1grid((N + 127) / 128, 1);
    const dim3 g4grid((N + 127) / 128, 4);
    const int aggGrid = (N + 3) / 4;
    const int waveGrid = (N + 3) / 4;
    const int nScan = N + 1;
    const int nb = (nScan + 1023) / 1024;

    // ---- weight prep + CSR build ----
    prep_weights<<<15, 256, 0, stream>>>(embW, keyW, qryW, valW, skpW,
                                         g1W, g2W, h1W, h2W,
                                         keyb, qryb, valb, skpb, Wt, biasCat);
    hipMemsetAsync(hist, 0, (size_t)N * sizeof(int), stream);
    hist_kernel<<<1024, 256, 0, stream>>>(dstA, hist, E);
    scan1_kernel<<<nb, 256, 0, stream>>>(hist, N, row, bsum, nScan);
    scan2_kernel<<<1, 64, 0, stream>>>(bsum, nb);
    scan3_kernel<<<nb, 256, 0, stream>>>(row, bsum, cur, nScan, N);
    scatter_kernel<<<1024, 256, 0, stream>>>(srcA, dstA, cur, perm, srcp, E);

    #define UNIT(u) (Wt + (size_t)(u) * 32768)

    // ---- embedding MLP: G -> bx -> b2 -> bx ----
    gemm_mfma<<<g1grid, 256, 0, stream>>>(G,  UNIT(0), embb + 0,    bx, N, DD, 1);
    gemm_mfma<<<g1grid, 256, 0, stream>>>(bx, UNIT(1), embb + DD,   b2, N, DD, 1);
    gemm_mfma<<<g1grid, 256, 0, stream>>>(b2, UNIT(2), embb + 2*DD, bx, N, DD, 1);

    // ---- conv layer 0: x=bx -> out b2 ----
    gemm_mfma<<<g4grid, 256, 0, stream>>>(bx, UNIT(3), biasCat, bfused, N, 512, 0);
    edge_agg6<<<aggGrid, 256, 0, stream>>>(row, srcp, ea, perm,
                                           edgW + 0, edgb + 0, bfused, b2, N);

    // ---- conv layer 1: x=b2 -> out bx ----
    gemm_mfma<<<g4grid, 256, 0, stream>>>(b2, UNIT(7), biasCat + 512, bfused, N, 512, 0);
    edge_agg6<<<aggGrid, 256, 0, stream>>>(row, srcp, ea, perm,
                                           edgW + 21*DD, edgb + DD, bfused, bx, N);

    // ---- graph linears: bx -> b2 (relu) -> bx ----
    gemm_mfma<<<g1grid, 256, 0, stream>>>(bx, UNIT(11), g1b, b2, N, DD, 1);
    gemm_mfma<<<g1grid, 256, 0, stream>>>(b2, UNIT(12), g2b, bx, N, DD, 0);

    // ---- graph mean -> cvec ----
    hipMemsetAsync(gsum, 0, DD * sizeof(float), stream);
    colsum_kernel<<<256, DD, 0, stream>>>(bx, gsum, N);
    cvec_kernel<<<1, DD, 0, stream>>>(gsum, h1W, h1b, cvec, 1.0f / (float)N);

    // ---- head: h1 (bias=cvec, relu) -> b2 ; h2 -> bx ; h3 -> out ----
    gemm_mfma<<<g1grid, 256, 0, stream>>>(bx, UNIT(13), cvec, b2, N, DD, 1);
    gemm_mfma<<<g1grid, 256, 0, stream>>>(b2, UNIT(14), h2b, bx, N, DD, 1);
    head3_kernel<<<waveGrid, 256, 0, stream>>>(bx, h3W, h3b, (float*)d_out, N);
}